// Round 4
// baseline (1049.830 us; speedup 1.0000x reference)
//
#include <hip/hip_runtime.h>

#define NEG_SLOPE 0.2f

// ---------------------------------------------------------------------------
__global__ void zero_kernel(int* __restrict__ p, int n) {
    int i = blockIdx.x * blockDim.x + threadIdx.x;
    if (i < n) p[i] = 0;
}

// ---------------------------------------------------------------------------
// Edge-index normalization + dst counting fused. int32/int64 detect on device.
// ---------------------------------------------------------------------------
__global__ void detect_convert_count_kernel(const void* __restrict__ ei_raw,
                                            int E, int* __restrict__ src32,
                                            int* __restrict__ dst32,
                                            int* __restrict__ cnt) {
    const int* as32 = (const int*)ei_raw;
    const long long* as64 = (const long long*)ei_raw;
    bool is64 = true;
    for (int i = 0; i < 16; ++i) {
        long long v = as64[i];
        if (!(v >= 0 && v < 2147483648LL)) { is64 = false; }
    }
    int i = blockIdx.x * blockDim.x + threadIdx.x;
    if (i < E) {
        int s, d;
        if (is64) {
            s = (int)as64[i];
            d = (int)as64[(size_t)E + i];
        } else {
            s = as32[i];
            d = as32[(size_t)E + i];
        }
        src32[i] = s;
        dst32[i] = d;
        atomicAdd(&cnt[d], 1);
    }
}

// ---------------------------------------------------------------------------
// Hierarchical exclusive scan cnt[N] -> off[N+1], cursor[N].
// ---------------------------------------------------------------------------
#define SCAN_NB 256

__global__ __launch_bounds__(256) void scan1_kernel(const int* __restrict__ cnt,
                                                    int* __restrict__ partial,
                                                    int N) {
    __shared__ int s[256];
    int b = blockIdx.x;
    int t = threadIdx.x;
    int csize = (N + SCAN_NB - 1) / SCAN_NB;
    int beg = b * csize;
    int end = min(beg + csize, N);
    int sum = 0;
    for (int i = beg + t; i < end; i += 256) sum += cnt[i];
    s[t] = sum;
    __syncthreads();
    for (int o = 128; o > 0; o >>= 1) {
        if (t < o) s[t] += s[t + o];
        __syncthreads();
    }
    if (t == 0) partial[b] = s[0];
}

__global__ __launch_bounds__(256) void scan2_kernel(int* __restrict__ partial,
                                                    int* __restrict__ off,
                                                    int N) {
    __shared__ int s[256];
    int t = threadIdx.x;
    int v = partial[t];
    s[t] = v;
    __syncthreads();
    for (int o = 1; o < 256; o <<= 1) {
        int add = (t >= o) ? s[t - o] : 0;
        __syncthreads();
        s[t] += add;
        __syncthreads();
    }
    partial[t] = s[t] - v;  // exclusive
    if (t == 255) off[N] = s[255];
}

__global__ __launch_bounds__(256) void scan3_kernel(const int* __restrict__ cnt,
                                                    const int* __restrict__ partial,
                                                    int* __restrict__ off,
                                                    int* __restrict__ cursor,
                                                    int N) {
    __shared__ int s[256];
    int b = blockIdx.x;
    int t = threadIdx.x;
    int csize = (N + SCAN_NB - 1) / SCAN_NB;
    int beg = b * csize;
    int end = min(beg + csize, N);
    int base = partial[b];
    for (int r = beg; r < end; r += 256) {
        int i = r + t;
        int v = (i < end) ? cnt[i] : 0;
        s[t] = v;
        __syncthreads();
        for (int o = 1; o < 256; o <<= 1) {
            int add = (t >= o) ? s[t - o] : 0;
            __syncthreads();
            s[t] += add;
            __syncthreads();
        }
        if (i < end) {
            int e = base + s[t] - v;
            off[i] = e;
            cursor[i] = e;
        }
        int roundsum = s[255];
        __syncthreads();
        base += roundsum;
    }
}

__global__ void scatter_kernel(const int* __restrict__ src,
                               const int* __restrict__ dst, int E,
                               int* __restrict__ cursor,
                               int* __restrict__ csr_src) {
    int i = blockIdx.x * blockDim.x + threadIdx.x;
    if (i < E) {
        int p = atomicAdd(&cursor[dst[i]], 1);
        csr_src[p] = src[i];
    }
}

// ---------------------------------------------------------------------------
// GEMM + fused alpha epilogue: H = X[N,128] @ W[128,128] and
// alpha_s[n,h] = h[n]·a_src[h], alpha_d likewise (shuffle-reduced from the
// per-thread 4x4 acc tiles — saves a separate 25.6MB h re-read pass).
// ---------------------------------------------------------------------------
template <int H>
__global__ __launch_bounds__(128) void gemm128_kernel(
    const float* __restrict__ X, const float* __restrict__ W,
    const float* __restrict__ asrc, const float* __restrict__ adst,
    float* __restrict__ Hout, float* __restrict__ alpha_s,
    float* __restrict__ alpha_d, int N) {
    __shared__ float sX[16 * 132];
    int t = threadIdx.x;
    int tx = t & 31;
    int ty = t >> 5;
    int row0 = blockIdx.x * 16;

    for (int i = t; i < 512; i += 128) {
        int r = i >> 5;
        int kq = i & 31;
        int row = row0 + r;
        float4 v = make_float4(0.f, 0.f, 0.f, 0.f);
        if (row < N) v = ((const float4*)X)[(size_t)row * 32 + kq];
        *(float4*)&sX[r * 132 + kq * 4] = v;
    }
    __syncthreads();

    float acc[4][4] = {};
    const float4* W4 = (const float4*)W;
#pragma unroll 4
    for (int k = 0; k < 128; ++k) {
        float4 b = W4[k * 32 + tx];
#pragma unroll
        for (int i = 0; i < 4; ++i) {
            float a = sX[(ty * 4 + i) * 132 + k];
            acc[i][0] += a * b.x;
            acc[i][1] += a * b.y;
            acc[i][2] += a * b.z;
            acc[i][3] += a * b.w;
        }
    }

    // store h
#pragma unroll
    for (int i = 0; i < 4; ++i) {
        int row = row0 + ty * 4 + i;
        if (row < N) {
            float4 o = make_float4(acc[i][0], acc[i][1], acc[i][2], acc[i][3]);
            ((float4*)Hout)[(size_t)row * 32 + tx] = o;
        }
    }

    // fused alpha: thread covers cols 4*tx..4*tx+3 of rows ty*4+i.
    constexpr int GB = (H == 4) ? 8 : 32;  // tx lanes per head
    float4 av = ((const float4*)asrc)[tx];
    float4 dv = ((const float4*)adst)[tx];
#pragma unroll
    for (int i = 0; i < 4; ++i) {
        float ps = acc[i][0] * av.x + acc[i][1] * av.y + acc[i][2] * av.z +
                   acc[i][3] * av.w;
        float pd = acc[i][0] * dv.x + acc[i][1] * dv.y + acc[i][2] * dv.z +
                   acc[i][3] * dv.w;
#pragma unroll
        for (int o = 1; o < GB; o <<= 1) {
            ps += __shfl_xor(ps, o);
            pd += __shfl_xor(pd, o);
        }
        if ((tx & (GB - 1)) == 0) {
            int row = row0 + ty * 4 + i;
            if (row < N) {
                int hh = tx / GB;
                alpha_s[(size_t)row * H + hh] = ps;
                alpha_d[(size_t)row * H + hh] = pd;
            }
        }
    }
}

// ---------------------------------------------------------------------------
// Softmax stats per node: m[h] = max over incident edges of leaky(as+ad),
// inv[h] = 1/sum(exp(s-m)). One wave per node. Writes float2 {m, inv}.
// ---------------------------------------------------------------------------
template <int H>
__global__ __launch_bounds__(128) void weight_kernel(
    const float* __restrict__ as_, const float* __restrict__ ad_,
    const int* __restrict__ off, const int* __restrict__ csr_src,
    float2* __restrict__ minv, int N) {
    int w = threadIdx.x >> 6;
    int lane = threadIdx.x & 63;
    int n = blockIdx.x * 2 + w;
    if (n >= N) return;

    int beg = off[n];
    int total = off[n + 1] - beg + 1;  // + self loop

    float adv[H];
#pragma unroll
    for (int hh = 0; hh < H; ++hh) adv[hh] = ad_[(size_t)n * H + hh];

    float m[H];
#pragma unroll
    for (int hh = 0; hh < H; ++hh) m[hh] = -3.4e38f;
    for (int idx = lane; idx < total; idx += 64) {
        int src = (idx == 0) ? n : csr_src[beg + idx - 1];
#pragma unroll
        for (int hh = 0; hh < H; ++hh) {
            float s = as_[(size_t)src * H + hh] + adv[hh];
            s = (s > 0.f) ? s : NEG_SLOPE * s;
            m[hh] = fmaxf(m[hh], s);
        }
    }
#pragma unroll
    for (int o = 32; o > 0; o >>= 1) {
#pragma unroll
        for (int hh = 0; hh < H; ++hh) m[hh] = fmaxf(m[hh], __shfl_xor(m[hh], o));
    }

    float dsum[H];
#pragma unroll
    for (int hh = 0; hh < H; ++hh) dsum[hh] = 0.f;
    for (int idx = lane; idx < total; idx += 64) {
        int src = (idx == 0) ? n : csr_src[beg + idx - 1];
#pragma unroll
        for (int hh = 0; hh < H; ++hh) {
            float s = as_[(size_t)src * H + hh] + adv[hh];
            s = (s > 0.f) ? s : NEG_SLOPE * s;
            dsum[hh] += __expf(s - m[hh]);
        }
    }
#pragma unroll
    for (int o = 32; o > 0; o >>= 1) {
#pragma unroll
        for (int hh = 0; hh < H; ++hh) dsum[hh] += __shfl_xor(dsum[hh], o);
    }
    if (lane < H) {
        // lane hh writes {m,inv} for head hh (lanes 0..H-1 hold full reduce)
        minv[(size_t)n * H + lane] =
            make_float2(m[lane], 1.f / dsum[lane]);
    }
}

// ---------------------------------------------------------------------------
// Channel-chunked aggregation. Chunk = 16 channels (h-slice 3.2MB < 4MB
// per-XCD L2). blockIdx.y = chunk (x-major dispatch => chunk-major sweep =>
// per-XCD L2 residency of the active slice; perf-only assumption).
// One wave per node; 64 lanes = 4 edge-slots x 16 channels.
// alpha recomputed inline from as_ (800KB, L2-resident) + per-node {m,inv}.
// ---------------------------------------------------------------------------
template <int H>
__global__ __launch_bounds__(128) void agg_kernel(
    const float* __restrict__ h, const float* __restrict__ as_,
    const float* __restrict__ ad_, const float2* __restrict__ minv,
    const int* __restrict__ off, const int* __restrict__ csr_src,
    const float* __restrict__ bias, float* __restrict__ out, int N) {
    int w = threadIdx.x >> 6;
    int lane = threadIdx.x & 63;
    int n = blockIdx.x * 2 + w;
    if (n >= N) return;
    int ck = blockIdx.y;                       // 0..7
    int hh = (H == 4) ? (ck >> 1) : 0;         // C=32: 2 chunks per head
    int es = lane >> 4;                        // edge slot 0..3
    int c = lane & 15;                         // channel within chunk

    int beg = off[n];
    int total = off[n + 1] - beg + 1;          // + self loop
    float advh = ad_[(size_t)n * H + hh];
    float2 mi = minv[(size_t)n * H + hh];

    const float* hcol = h + ck * 16 + c;
    float acc = 0.f;
    for (int base = 0; base < total; base += 4) {
        int idx = base + es;
        if (idx < total) {
            int src = (idx == 0) ? n : csr_src[beg + idx - 1];
            float s = as_[(size_t)src * H + hh] + advh;
            s = (s > 0.f) ? s : NEG_SLOPE * s;
            float a = __expf(s - mi.x) * mi.y;
            acc += a * hcol[(size_t)src * 128];
        }
    }
    acc += __shfl_xor(acc, 16);
    acc += __shfl_xor(acc, 32);
    if (lane < 16) {
        float v = acc + bias[ck * 16 + c];
        out[(size_t)n * 128 + ck * 16 + c] = fmaxf(v, 0.f);
    }
}

// ---------------------------------------------------------------------------
extern "C" void kernel_launch(void* const* d_in, const int* in_sizes, int n_in,
                              void* d_out, int out_size, void* d_ws,
                              size_t ws_size, hipStream_t stream) {
    const float* x   = (const float*)d_in[0];
    const void*  ei  = d_in[1];
    const float* W0  = (const float*)d_in[2];
    const float* as0 = (const float*)d_in[3];
    const float* ad0 = (const float*)d_in[4];
    const float* b0  = (const float*)d_in[5];
    const float* W1  = (const float*)d_in[6];
    const float* as1 = (const float*)d_in[7];
    const float* ad1 = (const float*)d_in[8];
    const float* b1  = (const float*)d_in[9];
    const float* W2  = (const float*)d_in[10];
    const float* as2 = (const float*)d_in[11];
    const float* ad2 = (const float*)d_in[12];
    const float* b2  = (const float*)d_in[13];

    int N = in_sizes[0] / 128;
    int E = in_sizes[1] / 2;
    float* out = (float*)d_out;

    // workspace layout (~40 MB)
    float*  h       = (float*)d_ws;                        // N*128
    float*  alpha_s = h + (size_t)N * 128;                 // N*4 (max H)
    float*  alpha_d = alpha_s + (size_t)N * 4;             // N*4
    float2* minv    = (float2*)(alpha_d + (size_t)N * 4);  // N*4 float2
    int*    cnt     = (int*)(minv + (size_t)N * 4);        // N
    int*    off     = cnt + N;                             // N+1
    int*    cursor  = off + N + 1;                         // N
    int*    partial = cursor + N;                          // SCAN_NB
    int*    src32   = partial + SCAN_NB;                   // E
    int*    dst32   = src32 + E;                           // E
    int*    csr     = dst32 + E;                           // E

    int eb = (E + 255) / 256;
    int nb = (N + 255) / 256;

    zero_kernel<<<nb, 256, 0, stream>>>(cnt, N);
    detect_convert_count_kernel<<<eb, 256, 0, stream>>>(ei, E, src32, dst32, cnt);
    scan1_kernel<<<SCAN_NB, 256, 0, stream>>>(cnt, partial, N);
    scan2_kernel<<<1, 256, 0, stream>>>(partial, off, N);
    scan3_kernel<<<SCAN_NB, 256, 0, stream>>>(cnt, partial, off, cursor, N);
    scatter_kernel<<<eb, 256, 0, stream>>>(src32, dst32, E, cursor, csr);

    int gb = (N + 15) / 16;
    int wb = (N + 1) / 2;  // 2 nodes (waves) per block
    dim3 ag(wb, 8);        // y = channel chunk

    // layer 0: H=4
    gemm128_kernel<4><<<gb, 128, 0, stream>>>(x, W0, as0, ad0, h, alpha_s, alpha_d, N);
    weight_kernel<4><<<wb, 128, 0, stream>>>(alpha_s, alpha_d, off, csr, minv, N);
    agg_kernel<4><<<ag, 128, 0, stream>>>(h, alpha_s, alpha_d, minv, off, csr, b0, out, N);

    // layer 1: H=4
    gemm128_kernel<4><<<gb, 128, 0, stream>>>(out, W1, as1, ad1, h, alpha_s, alpha_d, N);
    weight_kernel<4><<<wb, 128, 0, stream>>>(alpha_s, alpha_d, off, csr, minv, N);
    agg_kernel<4><<<ag, 128, 0, stream>>>(h, alpha_s, alpha_d, minv, off, csr, b1, out, N);

    // layer 2: H=1
    gemm128_kernel<1><<<gb, 128, 0, stream>>>(out, W2, as2, ad2, h, alpha_s, alpha_d, N);
    weight_kernel<1><<<wb, 128, 0, stream>>>(alpha_s, alpha_d, off, csr, minv, N);
    agg_kernel<1><<<ag, 128, 0, stream>>>(h, alpha_s, alpha_d, minv, off, csr, b2, out, N);
}

// Round 5
// 481.284 us; speedup vs baseline: 2.1813x; 2.1813x over previous
//
#include <hip/hip_runtime.h>

#define NEG_SLOPE 0.2f

// ---------------------------------------------------------------------------
__global__ void zero_kernel(int* __restrict__ p, int n) {
    int i = blockIdx.x * blockDim.x + threadIdx.x;
    if (i < n) p[i] = 0;
}

// ---------------------------------------------------------------------------
// Edge-index normalization + dst counting fused. int32/int64 detect on device.
// ---------------------------------------------------------------------------
__global__ void detect_convert_count_kernel(const void* __restrict__ ei_raw,
                                            int E, int* __restrict__ src32,
                                            int* __restrict__ dst32,
                                            int* __restrict__ cnt) {
    const int* as32 = (const int*)ei_raw;
    const long long* as64 = (const long long*)ei_raw;
    bool is64 = true;
    for (int i = 0; i < 16; ++i) {
        long long v = as64[i];
        if (!(v >= 0 && v < 2147483648LL)) { is64 = false; }
    }
    int i = blockIdx.x * blockDim.x + threadIdx.x;
    if (i < E) {
        int s, d;
        if (is64) {
            s = (int)as64[i];
            d = (int)as64[(size_t)E + i];
        } else {
            s = as32[i];
            d = as32[(size_t)E + i];
        }
        src32[i] = s;
        dst32[i] = d;
        atomicAdd(&cnt[d], 1);
    }
}

// ---------------------------------------------------------------------------
// Hierarchical exclusive scan cnt[N] -> off[N+1], cursor[N].
// ---------------------------------------------------------------------------
#define SCAN_NB 256

__global__ __launch_bounds__(256) void scan1_kernel(const int* __restrict__ cnt,
                                                    int* __restrict__ partial,
                                                    int N) {
    __shared__ int s[256];
    int b = blockIdx.x;
    int t = threadIdx.x;
    int csize = (N + SCAN_NB - 1) / SCAN_NB;
    int beg = b * csize;
    int end = min(beg + csize, N);
    int sum = 0;
    for (int i = beg + t; i < end; i += 256) sum += cnt[i];
    s[t] = sum;
    __syncthreads();
    for (int o = 128; o > 0; o >>= 1) {
        if (t < o) s[t] += s[t + o];
        __syncthreads();
    }
    if (t == 0) partial[b] = s[0];
}

__global__ __launch_bounds__(256) void scan2_kernel(int* __restrict__ partial,
                                                    int* __restrict__ off,
                                                    int N) {
    __shared__ int s[256];
    int t = threadIdx.x;
    int v = partial[t];
    s[t] = v;
    __syncthreads();
    for (int o = 1; o < 256; o <<= 1) {
        int add = (t >= o) ? s[t - o] : 0;
        __syncthreads();
        s[t] += add;
        __syncthreads();
    }
    partial[t] = s[t] - v;  // exclusive
    if (t == 255) off[N] = s[255];
}

__global__ __launch_bounds__(256) void scan3_kernel(const int* __restrict__ cnt,
                                                    const int* __restrict__ partial,
                                                    int* __restrict__ off,
                                                    int* __restrict__ cursor,
                                                    int N) {
    __shared__ int s[256];
    int b = blockIdx.x;
    int t = threadIdx.x;
    int csize = (N + SCAN_NB - 1) / SCAN_NB;
    int beg = b * csize;
    int end = min(beg + csize, N);
    int base = partial[b];
    for (int r = beg; r < end; r += 256) {
        int i = r + t;
        int v = (i < end) ? cnt[i] : 0;
        s[t] = v;
        __syncthreads();
        for (int o = 1; o < 256; o <<= 1) {
            int add = (t >= o) ? s[t - o] : 0;
            __syncthreads();
            s[t] += add;
            __syncthreads();
        }
        if (i < end) {
            int e = base + s[t] - v;
            off[i] = e;
            cursor[i] = e;
        }
        int roundsum = s[255];
        __syncthreads();
        base += roundsum;
    }
}

__global__ void scatter_kernel(const int* __restrict__ src,
                               const int* __restrict__ dst, int E,
                               int* __restrict__ cursor,
                               int* __restrict__ csr_src) {
    int i = blockIdx.x * blockDim.x + threadIdx.x;
    if (i < E) {
        int p = atomicAdd(&cursor[dst[i]], 1);
        csr_src[p] = src[i];
    }
}

// ---------------------------------------------------------------------------
// GEMM + fused alpha epilogue: H = X[N,128] @ W[128,128] and
// alpha_s[n,h] = h[n]·a_src[h], alpha_d likewise (shuffle-reduced from the
// per-thread 4x4 acc tiles).
// ---------------------------------------------------------------------------
template <int H>
__global__ __launch_bounds__(128) void gemm128_kernel(
    const float* __restrict__ X, const float* __restrict__ W,
    const float* __restrict__ asrc, const float* __restrict__ adst,
    float* __restrict__ Hout, float* __restrict__ alpha_s,
    float* __restrict__ alpha_d, int N) {
    __shared__ float sX[16 * 132];
    int t = threadIdx.x;
    int tx = t & 31;
    int ty = t >> 5;
    int row0 = blockIdx.x * 16;

    for (int i = t; i < 512; i += 128) {
        int r = i >> 5;
        int kq = i & 31;
        int row = row0 + r;
        float4 v = make_float4(0.f, 0.f, 0.f, 0.f);
        if (row < N) v = ((const float4*)X)[(size_t)row * 32 + kq];
        *(float4*)&sX[r * 132 + kq * 4] = v;
    }
    __syncthreads();

    float acc[4][4] = {};
    const float4* W4 = (const float4*)W;
#pragma unroll 4
    for (int k = 0; k < 128; ++k) {
        float4 b = W4[k * 32 + tx];
#pragma unroll
        for (int i = 0; i < 4; ++i) {
            float a = sX[(ty * 4 + i) * 132 + k];
            acc[i][0] += a * b.x;
            acc[i][1] += a * b.y;
            acc[i][2] += a * b.z;
            acc[i][3] += a * b.w;
        }
    }

#pragma unroll
    for (int i = 0; i < 4; ++i) {
        int row = row0 + ty * 4 + i;
        if (row < N) {
            float4 o = make_float4(acc[i][0], acc[i][1], acc[i][2], acc[i][3]);
            ((float4*)Hout)[(size_t)row * 32 + tx] = o;
        }
    }

    constexpr int GB = (H == 4) ? 8 : 32;  // tx lanes per head
    float4 av = ((const float4*)asrc)[tx];
    float4 dv = ((const float4*)adst)[tx];
#pragma unroll
    for (int i = 0; i < 4; ++i) {
        float ps = acc[i][0] * av.x + acc[i][1] * av.y + acc[i][2] * av.z +
                   acc[i][3] * av.w;
        float pd = acc[i][0] * dv.x + acc[i][1] * dv.y + acc[i][2] * dv.z +
                   acc[i][3] * dv.w;
#pragma unroll
        for (int o = 1; o < GB; o <<= 1) {
            ps += __shfl_xor(ps, o);
            pd += __shfl_xor(pd, o);
        }
        if ((tx & (GB - 1)) == 0) {
            int row = row0 + ty * 4 + i;
            if (row < N) {
                int hh = tx / GB;
                alpha_s[(size_t)row * H + hh] = ps;
                alpha_d[(size_t)row * H + hh] = pd;
            }
        }
    }
}

// ---------------------------------------------------------------------------
// Per-dst-node segment softmax + weighted aggregation, single softmax pass.
// One WAVE per node (2/block). Edge idx 0 = self-loop. First 64 edges' s and
// exp values stay in registers across max->sum->weights (degree<=64 fast
// path; generic fallback loops for larger degree). Accumulate loop is
// unrolled x4 for memory-level parallelism on the random 512B h-row reads.
// ---------------------------------------------------------------------------
template <int H>
__global__ __launch_bounds__(128) void gather_kernel(
    const float* __restrict__ h, const float* __restrict__ as_,
    const float* __restrict__ ad_, const int* __restrict__ off,
    const int* __restrict__ csr_src, const float* __restrict__ bias,
    float* __restrict__ out, int N) {
    constexpr int C = 128 / H;
    __shared__ int s_src[2][64];
    __shared__ float s_w[2][64 * H];
    int w = threadIdx.x >> 6;
    int lane = threadIdx.x & 63;
    int n = blockIdx.x * 2 + w;
    if (n >= N) return;

    int beg = off[n];
    int total = off[n + 1] - beg + 1;  // + self loop
    int total0 = min(total, 64);

    float adv[H];
#pragma unroll
    for (int hh = 0; hh < H; ++hh) adv[hh] = ad_[(size_t)n * H + hh];

    // Phase A: first chunk -> registers (sv), stage src; running per-head max
    float sv[H];
    float m[H];
#pragma unroll
    for (int hh = 0; hh < H; ++hh) m[hh] = -3.4e38f;
    if (lane < total0) {
        int src = (lane == 0) ? n : csr_src[beg + lane - 1];
        s_src[w][lane] = src;
        if (H == 4) {
            float4 a4 = ((const float4*)as_)[src];
            sv[0] = a4.x + adv[0];
            sv[1] = a4.y + adv[1];
            sv[2] = a4.z + adv[2];
            sv[3] = a4.w + adv[3];
        } else {
            sv[0] = as_[src] + adv[0];
        }
#pragma unroll
        for (int hh = 0; hh < H; ++hh) {
            float s = sv[hh];
            s = (s > 0.f) ? s : NEG_SLOPE * s;
            sv[hh] = s;
            m[hh] = s;
        }
    }
    for (int idx = lane + 64; idx < total; idx += 64) {  // degree>64 fallback
        int src = csr_src[beg + idx - 1];
#pragma unroll
        for (int hh = 0; hh < H; ++hh) {
            float s = as_[(size_t)src * H + hh] + adv[hh];
            s = (s > 0.f) ? s : NEG_SLOPE * s;
            m[hh] = fmaxf(m[hh], s);
        }
    }
#pragma unroll
    for (int o = 32; o > 0; o >>= 1)
#pragma unroll
        for (int hh = 0; hh < H; ++hh) m[hh] = fmaxf(m[hh], __shfl_xor(m[hh], o));

    // Phase B: sum of exp (first chunk from registers)
    float p[H];
    float dsum[H];
#pragma unroll
    for (int hh = 0; hh < H; ++hh) dsum[hh] = 0.f;
    if (lane < total0) {
#pragma unroll
        for (int hh = 0; hh < H; ++hh) {
            p[hh] = __expf(sv[hh] - m[hh]);
            dsum[hh] = p[hh];
        }
    }
    for (int idx = lane + 64; idx < total; idx += 64) {
        int src = csr_src[beg + idx - 1];
#pragma unroll
        for (int hh = 0; hh < H; ++hh) {
            float s = as_[(size_t)src * H + hh] + adv[hh];
            s = (s > 0.f) ? s : NEG_SLOPE * s;
            dsum[hh] += __expf(s - m[hh]);
        }
    }
#pragma unroll
    for (int o = 32; o > 0; o >>= 1)
#pragma unroll
        for (int hh = 0; hh < H; ++hh) dsum[hh] += __shfl_xor(dsum[hh], o);
    float inv[H];
#pragma unroll
    for (int hh = 0; hh < H; ++hh) inv[hh] = 1.f / dsum[hh];

    // stage final weights for first chunk
    if (lane < total0) {
#pragma unroll
        for (int hh = 0; hh < H; ++hh) s_w[w][lane * H + hh] = p[hh] * inv[hh];
    }

    // Phase C: weighted accumulation (lane owns channels 2*lane, 2*lane+1)
    const int head_t = (2 * lane) / C;
    float2 acc = make_float2(0.f, 0.f);
    const float2* __restrict__ h2 = (const float2*)h;
    for (int base = 0; base < total; base += 64) {
        int cnt2 = min(64, total - base);
        if (base > 0 && lane < cnt2) {  // degree>64 fallback: restage
            int src = csr_src[beg + base + lane - 1];
            s_src[w][lane] = src;
#pragma unroll
            for (int hh = 0; hh < H; ++hh) {
                float s = as_[(size_t)src * H + hh] + adv[hh];
                s = (s > 0.f) ? s : NEG_SLOPE * s;
                s_w[w][lane * H + hh] = __expf(s - m[hh]) * inv[hh];
            }
        }
        __builtin_amdgcn_wave_barrier();
        int j = 0;
        for (; j + 4 <= cnt2; j += 4) {
            int t0 = s_src[w][j + 0], t1 = s_src[w][j + 1];
            int t2 = s_src[w][j + 2], t3 = s_src[w][j + 3];
            float w0 = s_w[w][(j + 0) * H + head_t];
            float w1 = s_w[w][(j + 1) * H + head_t];
            float w2 = s_w[w][(j + 2) * H + head_t];
            float w3 = s_w[w][(j + 3) * H + head_t];
            float2 h0 = h2[(size_t)t0 * 64 + lane];
            float2 h1 = h2[(size_t)t1 * 64 + lane];
            float2 h2v = h2[(size_t)t2 * 64 + lane];
            float2 h3 = h2[(size_t)t3 * 64 + lane];
            acc.x += w0 * h0.x; acc.y += w0 * h0.y;
            acc.x += w1 * h1.x; acc.y += w1 * h1.y;
            acc.x += w2 * h2v.x; acc.y += w2 * h2v.y;
            acc.x += w3 * h3.x; acc.y += w3 * h3.y;
        }
        for (; j < cnt2; ++j) {
            int sj = s_src[w][j];
            float wj = s_w[w][j * H + head_t];
            float2 hv = h2[(size_t)sj * 64 + lane];
            acc.x += wj * hv.x;
            acc.y += wj * hv.y;
        }
        __builtin_amdgcn_wave_barrier();
    }
    float2 bv = ((const float2*)bias)[lane];
    float2 o2;
    o2.x = fmaxf(acc.x + bv.x, 0.f);
    o2.y = fmaxf(acc.y + bv.y, 0.f);
    ((float2*)out)[(size_t)n * 64 + lane] = o2;
}

// ---------------------------------------------------------------------------
extern "C" void kernel_launch(void* const* d_in, const int* in_sizes, int n_in,
                              void* d_out, int out_size, void* d_ws,
                              size_t ws_size, hipStream_t stream) {
    const float* x   = (const float*)d_in[0];
    const void*  ei  = d_in[1];
    const float* W0  = (const float*)d_in[2];
    const float* as0 = (const float*)d_in[3];
    const float* ad0 = (const float*)d_in[4];
    const float* b0  = (const float*)d_in[5];
    const float* W1  = (const float*)d_in[6];
    const float* as1 = (const float*)d_in[7];
    const float* ad1 = (const float*)d_in[8];
    const float* b1  = (const float*)d_in[9];
    const float* W2  = (const float*)d_in[10];
    const float* as2 = (const float*)d_in[11];
    const float* ad2 = (const float*)d_in[12];
    const float* b2  = (const float*)d_in[13];

    int N = in_sizes[0] / 128;
    int E = in_sizes[1] / 2;
    float* out = (float*)d_out;

    // workspace layout
    float* h       = (float*)d_ws;                       // N*128
    float* alpha_s = h + (size_t)N * 128;                // N*4 (max H)
    float* alpha_d = alpha_s + (size_t)N * 4;            // N*4
    int*   cnt     = (int*)(alpha_d + (size_t)N * 4);    // N
    int*   off     = cnt + N;                            // N+1
    int*   cursor  = off + N + 1;                        // N
    int*   partial = cursor + N;                         // SCAN_NB
    int*   src32   = partial + SCAN_NB;                  // E
    int*   dst32   = src32 + E;                          // E
    int*   csr     = dst32 + E;                          // E

    int eb = (E + 255) / 256;
    int nb = (N + 255) / 256;

    zero_kernel<<<nb, 256, 0, stream>>>(cnt, N);
    detect_convert_count_kernel<<<eb, 256, 0, stream>>>(ei, E, src32, dst32, cnt);
    scan1_kernel<<<SCAN_NB, 256, 0, stream>>>(cnt, partial, N);
    scan2_kernel<<<1, 256, 0, stream>>>(partial, off, N);
    scan3_kernel<<<SCAN_NB, 256, 0, stream>>>(cnt, partial, off, cursor, N);
    scatter_kernel<<<eb, 256, 0, stream>>>(src32, dst32, E, cursor, csr);

    int gb = (N + 15) / 16;
    int wb = (N + 1) / 2;  // 2 nodes (waves) per block

    // layer 0: H=4
    gemm128_kernel<4><<<gb, 128, 0, stream>>>(x, W0, as0, ad0, h, alpha_s, alpha_d, N);
    gather_kernel<4><<<wb, 128, 0, stream>>>(h, alpha_s, alpha_d, off, csr, b0, out, N);

    // layer 1: H=4
    gemm128_kernel<4><<<gb, 128, 0, stream>>>(out, W1, as1, ad1, h, alpha_s, alpha_d, N);
    gather_kernel<4><<<wb, 128, 0, stream>>>(h, alpha_s, alpha_d, off, csr, b1, out, N);

    // layer 2: H=1
    gemm128_kernel<1><<<gb, 128, 0, stream>>>(out, W2, as2, ad2, h, alpha_s, alpha_d, N);
    gather_kernel<1><<<wb, 128, 0, stream>>>(h, alpha_s, alpha_d, off, csr, b2, out, N);
}

// Round 6
// 481.026 us; speedup vs baseline: 2.1825x; 1.0005x over previous
//
#include <hip/hip_runtime.h>

#define NEG_SLOPE 0.2f

// ---------------------------------------------------------------------------
__global__ void zero_kernel(int* __restrict__ p, int n) {
    int i = blockIdx.x * blockDim.x + threadIdx.x;
    if (i < n) p[i] = 0;
}

// ---------------------------------------------------------------------------
// Edge-index normalization + dst counting fused. int32/int64 detect on device.
// ---------------------------------------------------------------------------
__global__ void detect_convert_count_kernel(const void* __restrict__ ei_raw,
                                            int E, int* __restrict__ src32,
                                            int* __restrict__ dst32,
                                            int* __restrict__ cnt) {
    const int* as32 = (const int*)ei_raw;
    const long long* as64 = (const long long*)ei_raw;
    bool is64 = true;
    for (int i = 0; i < 16; ++i) {
        long long v = as64[i];
        if (!(v >= 0 && v < 2147483648LL)) { is64 = false; }
    }
    int i = blockIdx.x * blockDim.x + threadIdx.x;
    if (i < E) {
        int s, d;
        if (is64) {
            s = (int)as64[i];
            d = (int)as64[(size_t)E + i];
        } else {
            s = as32[i];
            d = as32[(size_t)E + i];
        }
        src32[i] = s;
        dst32[i] = d;
        atomicAdd(&cnt[d], 1);
    }
}

// ---------------------------------------------------------------------------
// Hierarchical exclusive scan cnt[N] -> off[N+1], cursor[N].
// ---------------------------------------------------------------------------
#define SCAN_NB 256

__global__ __launch_bounds__(256) void scan1_kernel(const int* __restrict__ cnt,
                                                    int* __restrict__ partial,
                                                    int N) {
    __shared__ int s[256];
    int b = blockIdx.x;
    int t = threadIdx.x;
    int csize = (N + SCAN_NB - 1) / SCAN_NB;
    int beg = b * csize;
    int end = min(beg + csize, N);
    int sum = 0;
    for (int i = beg + t; i < end; i += 256) sum += cnt[i];
    s[t] = sum;
    __syncthreads();
    for (int o = 128; o > 0; o >>= 1) {
        if (t < o) s[t] += s[t + o];
        __syncthreads();
    }
    if (t == 0) partial[b] = s[0];
}

__global__ __launch_bounds__(256) void scan2_kernel(int* __restrict__ partial,
                                                    int* __restrict__ off,
                                                    int N) {
    __shared__ int s[256];
    int t = threadIdx.x;
    int v = partial[t];
    s[t] = v;
    __syncthreads();
    for (int o = 1; o < 256; o <<= 1) {
        int add = (t >= o) ? s[t - o] : 0;
        __syncthreads();
        s[t] += add;
        __syncthreads();
    }
    partial[t] = s[t] - v;  // exclusive
    if (t == 255) off[N] = s[255];
}

__global__ __launch_bounds__(256) void scan3_kernel(const int* __restrict__ cnt,
                                                    const int* __restrict__ partial,
                                                    int* __restrict__ off,
                                                    int* __restrict__ cursor,
                                                    int N) {
    __shared__ int s[256];
    int b = blockIdx.x;
    int t = threadIdx.x;
    int csize = (N + SCAN_NB - 1) / SCAN_NB;
    int beg = b * csize;
    int end = min(beg + csize, N);
    int base = partial[b];
    for (int r = beg; r < end; r += 256) {
        int i = r + t;
        int v = (i < end) ? cnt[i] : 0;
        s[t] = v;
        __syncthreads();
        for (int o = 1; o < 256; o <<= 1) {
            int add = (t >= o) ? s[t - o] : 0;
            __syncthreads();
            s[t] += add;
            __syncthreads();
        }
        if (i < end) {
            int e = base + s[t] - v;
            off[i] = e;
            cursor[i] = e;
        }
        int roundsum = s[255];
        __syncthreads();
        base += roundsum;
    }
}

__global__ void scatter_kernel(const int* __restrict__ src,
                               const int* __restrict__ dst, int E,
                               int* __restrict__ cursor,
                               int* __restrict__ csr_src) {
    int i = blockIdx.x * blockDim.x + threadIdx.x;
    if (i < E) {
        int p = atomicAdd(&cursor[dst[i]], 1);
        csr_src[p] = src[i];
    }
}

// ---------------------------------------------------------------------------
// GEMM + fused alpha epilogue, FMA-bound version.
// 256 threads; block tile 64 rows x 128 cols; thread tile 4 rows x 8 cols.
// X tile (64x128) and W (staged in two K=64 phases) both in LDS, stride 132
// (16B-aligned b128 reads; row-lane stride 4 banks -> 2-way, free; B-col
// lane stride 8 banks -> 4-way, 1.58x on 8/12 reads, still < VALU time).
// Rows per thread are strided by 16 (i*16+ty) for conflict-free A reads.
// ---------------------------------------------------------------------------
template <int H>
__global__ __launch_bounds__(256) void gemm128_kernel(
    const float* __restrict__ X, const float* __restrict__ W,
    const float* __restrict__ asrc, const float* __restrict__ adst,
    float* __restrict__ Hout, float* __restrict__ alpha_s,
    float* __restrict__ alpha_d, int N) {
    __shared__ float sX[64 * 132];
    __shared__ float sW[64 * 132];
    int t = threadIdx.x;
    int tx = t & 15;   // 16 col-groups x 8 cols
    int ty = t >> 4;   // 16 row-groups x 4 strided rows
    int row0 = blockIdx.x * 64;

    // stage X tile: 64 rows x 32 float4, coalesced
    const float4* X4 = (const float4*)X;
#pragma unroll
    for (int it = 0; it < 8; ++it) {
        int idx = t + it * 256;
        int r = idx >> 5;
        int q = idx & 31;
        int row = row0 + r;
        float4 v = make_float4(0.f, 0.f, 0.f, 0.f);
        if (row < N) v = X4[(size_t)row * 32 + q];
        *(float4*)&sX[r * 132 + q * 4] = v;
    }

    float acc[4][8] = {};
    const float4* W4 = (const float4*)W;

    for (int p = 0; p < 2; ++p) {
        // stage W rows [p*64, p*64+64)
#pragma unroll
        for (int it = 0; it < 8; ++it) {
            int idx = t + it * 256;
            int kk = idx >> 5;
            int q = idx & 31;
            float4 v = W4[(p * 64 + kk) * 32 + q];
            *(float4*)&sW[kk * 132 + q * 4] = v;
        }
        __syncthreads();

        for (int k4 = 0; k4 < 64; k4 += 4) {
            float4 a[4];
#pragma unroll
            for (int i = 0; i < 4; ++i)
                a[i] = *(const float4*)&sX[(i * 16 + ty) * 132 + p * 64 + k4];
#pragma unroll
            for (int kk = 0; kk < 4; ++kk) {
                float4 b0 = *(const float4*)&sW[(k4 + kk) * 132 + tx * 8];
                float4 b1 = *(const float4*)&sW[(k4 + kk) * 132 + tx * 8 + 4];
#pragma unroll
                for (int i = 0; i < 4; ++i) {
                    float av = ((const float*)&a[i])[kk];
                    acc[i][0] += av * b0.x;
                    acc[i][1] += av * b0.y;
                    acc[i][2] += av * b0.z;
                    acc[i][3] += av * b0.w;
                    acc[i][4] += av * b1.x;
                    acc[i][5] += av * b1.y;
                    acc[i][6] += av * b1.z;
                    acc[i][7] += av * b1.w;
                }
            }
        }
        __syncthreads();
    }

    // store h: 2 float4 per row
#pragma unroll
    for (int i = 0; i < 4; ++i) {
        int row = row0 + i * 16 + ty;
        if (row < N) {
            float4 o0 = make_float4(acc[i][0], acc[i][1], acc[i][2], acc[i][3]);
            float4 o1 = make_float4(acc[i][4], acc[i][5], acc[i][6], acc[i][7]);
            ((float4*)Hout)[(size_t)row * 32 + tx * 2] = o0;
            ((float4*)Hout)[(size_t)row * 32 + tx * 2 + 1] = o1;
        }
    }

    // fused alpha: thread covers cols tx*8..tx*8+7 (all within one head).
    constexpr int RW = (H == 4) ? 4 : 16;  // tx lanes per head (C/8)
    float4 av0 = ((const float4*)asrc)[tx * 2];
    float4 av1 = ((const float4*)asrc)[tx * 2 + 1];
    float4 dv0 = ((const float4*)adst)[tx * 2];
    float4 dv1 = ((const float4*)adst)[tx * 2 + 1];
#pragma unroll
    for (int i = 0; i < 4; ++i) {
        float ps = acc[i][0] * av0.x + acc[i][1] * av0.y + acc[i][2] * av0.z +
                   acc[i][3] * av0.w + acc[i][4] * av1.x + acc[i][5] * av1.y +
                   acc[i][6] * av1.z + acc[i][7] * av1.w;
        float pd = acc[i][0] * dv0.x + acc[i][1] * dv0.y + acc[i][2] * dv0.z +
                   acc[i][3] * dv0.w + acc[i][4] * dv1.x + acc[i][5] * dv1.y +
                   acc[i][6] * dv1.z + acc[i][7] * dv1.w;
#pragma unroll
        for (int o = 1; o < RW; o <<= 1) {
            ps += __shfl_xor(ps, o);
            pd += __shfl_xor(pd, o);
        }
        if ((tx & (RW - 1)) == 0) {
            int row = row0 + i * 16 + ty;
            if (row < N) {
                int hh = tx / RW;
                alpha_s[(size_t)row * H + hh] = ps;
                alpha_d[(size_t)row * H + hh] = pd;
            }
        }
    }
}

// ---------------------------------------------------------------------------
// Per-dst-node segment softmax + weighted aggregation, single softmax pass.
// One WAVE per node (2/block). Edge idx 0 = self-loop. Degree<=64 fast path
// keeps s/exp in registers; fallback loops for larger degree. Accumulate
// loop unrolled x4 for MLP on the random 512B h-row reads.
// ---------------------------------------------------------------------------
template <int H>
__global__ __launch_bounds__(128) void gather_kernel(
    const float* __restrict__ h, const float* __restrict__ as_,
    const float* __restrict__ ad_, const int* __restrict__ off,
    const int* __restrict__ csr_src, const float* __restrict__ bias,
    float* __restrict__ out, int N) {
    constexpr int C = 128 / H;
    __shared__ int s_src[2][64];
    __shared__ float s_w[2][64 * H];
    int w = threadIdx.x >> 6;
    int lane = threadIdx.x & 63;
    int n = blockIdx.x * 2 + w;
    if (n >= N) return;

    int beg = off[n];
    int total = off[n + 1] - beg + 1;  // + self loop
    int total0 = min(total, 64);

    float adv[H];
#pragma unroll
    for (int hh = 0; hh < H; ++hh) adv[hh] = ad_[(size_t)n * H + hh];

    float sv[H];
    float m[H];
#pragma unroll
    for (int hh = 0; hh < H; ++hh) m[hh] = -3.4e38f;
    if (lane < total0) {
        int src = (lane == 0) ? n : csr_src[beg + lane - 1];
        s_src[w][lane] = src;
        if (H == 4) {
            float4 a4 = ((const float4*)as_)[src];
            sv[0] = a4.x + adv[0];
            sv[1] = a4.y + adv[1];
            sv[2] = a4.z + adv[2];
            sv[3] = a4.w + adv[3];
        } else {
            sv[0] = as_[src] + adv[0];
        }
#pragma unroll
        for (int hh = 0; hh < H; ++hh) {
            float s = sv[hh];
            s = (s > 0.f) ? s : NEG_SLOPE * s;
            sv[hh] = s;
            m[hh] = s;
        }
    }
    for (int idx = lane + 64; idx < total; idx += 64) {
        int src = csr_src[beg + idx - 1];
#pragma unroll
        for (int hh = 0; hh < H; ++hh) {
            float s = as_[(size_t)src * H + hh] + adv[hh];
            s = (s > 0.f) ? s : NEG_SLOPE * s;
            m[hh] = fmaxf(m[hh], s);
        }
    }
#pragma unroll
    for (int o = 32; o > 0; o >>= 1)
#pragma unroll
        for (int hh = 0; hh < H; ++hh) m[hh] = fmaxf(m[hh], __shfl_xor(m[hh], o));

    float p[H];
    float dsum[H];
#pragma unroll
    for (int hh = 0; hh < H; ++hh) dsum[hh] = 0.f;
    if (lane < total0) {
#pragma unroll
        for (int hh = 0; hh < H; ++hh) {
            p[hh] = __expf(sv[hh] - m[hh]);
            dsum[hh] = p[hh];
        }
    }
    for (int idx = lane + 64; idx < total; idx += 64) {
        int src = csr_src[beg + idx - 1];
#pragma unroll
        for (int hh = 0; hh < H; ++hh) {
            float s = as_[(size_t)src * H + hh] + adv[hh];
            s = (s > 0.f) ? s : NEG_SLOPE * s;
            dsum[hh] += __expf(s - m[hh]);
        }
    }
#pragma unroll
    for (int o = 32; o > 0; o >>= 1)
#pragma unroll
        for (int hh = 0; hh < H; ++hh) dsum[hh] += __shfl_xor(dsum[hh], o);
    float inv[H];
#pragma unroll
    for (int hh = 0; hh < H; ++hh) inv[hh] = 1.f / dsum[hh];

    if (lane < total0) {
#pragma unroll
        for (int hh = 0; hh < H; ++hh) s_w[w][lane * H + hh] = p[hh] * inv[hh];
    }

    const int head_t = (2 * lane) / C;
    float2 acc = make_float2(0.f, 0.f);
    const float2* __restrict__ h2 = (const float2*)h;
    for (int base = 0; base < total; base += 64) {
        int cnt2 = min(64, total - base);
        if (base > 0 && lane < cnt2) {
            int src = csr_src[beg + base + lane - 1];
            s_src[w][lane] = src;
#pragma unroll
            for (int hh = 0; hh < H; ++hh) {
                float s = as_[(size_t)src * H + hh] + adv[hh];
                s = (s > 0.f) ? s : NEG_SLOPE * s;
                s_w[w][lane * H + hh] = __expf(s - m[hh]) * inv[hh];
            }
        }
        __builtin_amdgcn_wave_barrier();
        int j = 0;
        for (; j + 4 <= cnt2; j += 4) {
            int t0 = s_src[w][j + 0], t1 = s_src[w][j + 1];
            int t2 = s_src[w][j + 2], t3 = s_src[w][j + 3];
            float w0 = s_w[w][(j + 0) * H + head_t];
            float w1 = s_w[w][(j + 1) * H + head_t];
            float w2 = s_w[w][(j + 2) * H + head_t];
            float w3 = s_w[w][(j + 3) * H + head_t];
            float2 h0 = h2[(size_t)t0 * 64 + lane];
            float2 h1 = h2[(size_t)t1 * 64 + lane];
            float2 h2v = h2[(size_t)t2 * 64 + lane];
            float2 h3 = h2[(size_t)t3 * 64 + lane];
            acc.x += w0 * h0.x; acc.y += w0 * h0.y;
            acc.x += w1 * h1.x; acc.y += w1 * h1.y;
            acc.x += w2 * h2v.x; acc.y += w2 * h2v.y;
            acc.x += w3 * h3.x; acc.y += w3 * h3.y;
        }
        for (; j < cnt2; ++j) {
            int sj = s_src[w][j];
            float wj = s_w[w][j * H + head_t];
            float2 hv = h2[(size_t)sj * 64 + lane];
            acc.x += wj * hv.x;
            acc.y += wj * hv.y;
        }
        __builtin_amdgcn_wave_barrier();
    }
    float2 bv = ((const float2*)bias)[lane];
    float2 o2;
    o2.x = fmaxf(acc.x + bv.x, 0.f);
    o2.y = fmaxf(acc.y + bv.y, 0.f);
    ((float2*)out)[(size_t)n * 64 + lane] = o2;
}

// ---------------------------------------------------------------------------
extern "C" void kernel_launch(void* const* d_in, const int* in_sizes, int n_in,
                              void* d_out, int out_size, void* d_ws,
                              size_t ws_size, hipStream_t stream) {
    const float* x   = (const float*)d_in[0];
    const void*  ei  = d_in[1];
    const float* W0  = (const float*)d_in[2];
    const float* as0 = (const float*)d_in[3];
    const float* ad0 = (const float*)d_in[4];
    const float* b0  = (const float*)d_in[5];
    const float* W1  = (const float*)d_in[6];
    const float* as1 = (const float*)d_in[7];
    const float* ad1 = (const float*)d_in[8];
    const float* b1  = (const float*)d_in[9];
    const float* W2  = (const float*)d_in[10];
    const float* as2 = (const float*)d_in[11];
    const float* ad2 = (const float*)d_in[12];
    const float* b2  = (const float*)d_in[13];

    int N = in_sizes[0] / 128;
    int E = in_sizes[1] / 2;
    float* out = (float*)d_out;

    // workspace layout
    float* h       = (float*)d_ws;                       // N*128
    float* alpha_s = h + (size_t)N * 128;                // N*4 (max H)
    float* alpha_d = alpha_s + (size_t)N * 4;            // N*4
    int*   cnt     = (int*)(alpha_d + (size_t)N * 4);    // N
    int*   off     = cnt + N;                            // N+1
    int*   cursor  = off + N + 1;                        // N
    int*   partial = cursor + N;                         // SCAN_NB
    int*   src32   = partial + SCAN_NB;                  // E
    int*   dst32   = src32 + E;                          // E
    int*   csr     = dst32 + E;                          // E

    int eb = (E + 255) / 256;
    int nb = (N + 255) / 256;

    zero_kernel<<<nb, 256, 0, stream>>>(cnt, N);
    detect_convert_count_kernel<<<eb, 256, 0, stream>>>(ei, E, src32, dst32, cnt);
    scan1_kernel<<<SCAN_NB, 256, 0, stream>>>(cnt, partial, N);
    scan2_kernel<<<1, 256, 0, stream>>>(partial, off, N);
    scan3_kernel<<<SCAN_NB, 256, 0, stream>>>(cnt, partial, off, cursor, N);
    scatter_kernel<<<eb, 256, 0, stream>>>(src32, dst32, E, cursor, csr);

    int gb = (N + 63) / 64;
    int wb = (N + 1) / 2;  // 2 nodes (waves) per block

    // layer 0: H=4
    gemm128_kernel<4><<<gb, 256, 0, stream>>>(x, W0, as0, ad0, h, alpha_s, alpha_d, N);
    gather_kernel<4><<<wb, 128, 0, stream>>>(h, alpha_s, alpha_d, off, csr, b0, out, N);

    // layer 1: H=4
    gemm128_kernel<4><<<gb, 256, 0, stream>>>(out, W1, as1, ad1, h, alpha_s, alpha_d, N);
    gather_kernel<4><<<wb, 128, 0, stream>>>(h, alpha_s, alpha_d, off, csr, b1, out, N);

    // layer 2: H=1
    gemm128_kernel<1><<<gb, 256, 0, stream>>>(out, W2, as2, ad2, h, alpha_s, alpha_d, N);
    gather_kernel<1><<<wb, 128, 0, stream>>>(h, alpha_s, alpha_d, off, csr, b2, out, N);
}

// Round 7
// 471.478 us; speedup vs baseline: 2.2267x; 1.0203x over previous
//
#include <hip/hip_runtime.h>

#define NEG_SLOPE 0.2f

// ---------------------------------------------------------------------------
__global__ void zero_kernel(int* __restrict__ p, int n) {
    int i = blockIdx.x * blockDim.x + threadIdx.x;
    if (i < n) p[i] = 0;
}

// ---------------------------------------------------------------------------
// Edge-index normalization + dst counting fused. int32/int64 detect on device.
// ---------------------------------------------------------------------------
__global__ void detect_convert_count_kernel(const void* __restrict__ ei_raw,
                                            int E, int* __restrict__ src32,
                                            int* __restrict__ dst32,
                                            int* __restrict__ cnt) {
    const int* as32 = (const int*)ei_raw;
    const long long* as64 = (const long long*)ei_raw;
    bool is64 = true;
    for (int i = 0; i < 16; ++i) {
        long long v = as64[i];
        if (!(v >= 0 && v < 2147483648LL)) { is64 = false; }
    }
    int i = blockIdx.x * blockDim.x + threadIdx.x;
    if (i < E) {
        int s, d;
        if (is64) {
            s = (int)as64[i];
            d = (int)as64[(size_t)E + i];
        } else {
            s = as32[i];
            d = as32[(size_t)E + i];
        }
        src32[i] = s;
        dst32[i] = d;
        atomicAdd(&cnt[d], 1);
    }
}

// ---------------------------------------------------------------------------
// Scan: scan1 computes 256 chunk partial sums; scan3 re-scans the partials
// in-block (256 ints -- cheaper than a separate 1-block kernel + launch gap)
// then scans its chunk locally. cnt[N] -> off[N+1], cursor[N].
// ---------------------------------------------------------------------------
#define SCAN_NB 256

__global__ __launch_bounds__(256) void scan1_kernel(const int* __restrict__ cnt,
                                                    int* __restrict__ partial,
                                                    int N) {
    __shared__ int s[256];
    int b = blockIdx.x;
    int t = threadIdx.x;
    int csize = (N + SCAN_NB - 1) / SCAN_NB;
    int beg = b * csize;
    int end = min(beg + csize, N);
    int sum = 0;
    for (int i = beg + t; i < end; i += 256) sum += cnt[i];
    s[t] = sum;
    __syncthreads();
    for (int o = 128; o > 0; o >>= 1) {
        if (t < o) s[t] += s[t + o];
        __syncthreads();
    }
    if (t == 0) partial[b] = s[0];
}

__global__ __launch_bounds__(256) void scan3_kernel(const int* __restrict__ cnt,
                                                    const int* __restrict__ partial,
                                                    int* __restrict__ off,
                                                    int* __restrict__ cursor,
                                                    int N) {
    __shared__ int sp[256];
    __shared__ int s[256];
    int b = blockIdx.x;
    int t = threadIdx.x;
    // in-block scan of the 256 partials (inclusive)
    int pv = partial[t];
    sp[t] = pv;
    __syncthreads();
    for (int o = 1; o < 256; o <<= 1) {
        int add = (t >= o) ? sp[t - o] : 0;
        __syncthreads();
        sp[t] += add;
        __syncthreads();
    }
    if (b == 0 && t == 0) off[N] = sp[255];
    int base = sp[b] - partial[b];  // exclusive prefix for this block's chunk

    int csize = (N + SCAN_NB - 1) / SCAN_NB;
    int beg = b * csize;
    int end = min(beg + csize, N);
    for (int r = beg; r < end; r += 256) {
        int i = r + t;
        int v = (i < end) ? cnt[i] : 0;
        s[t] = v;
        __syncthreads();
        for (int o = 1; o < 256; o <<= 1) {
            int add = (t >= o) ? s[t - o] : 0;
            __syncthreads();
            s[t] += add;
            __syncthreads();
        }
        if (i < end) {
            int e = base + s[t] - v;
            off[i] = e;
            cursor[i] = e;
        }
        int roundsum = s[255];
        __syncthreads();
        base += roundsum;
    }
}

__global__ void scatter_kernel(const int* __restrict__ src,
                               const int* __restrict__ dst, int E,
                               int* __restrict__ cursor,
                               int* __restrict__ csr_src) {
    int i = blockIdx.x * blockDim.x + threadIdx.x;
    if (i < E) {
        int p = atomicAdd(&cursor[dst[i]], 1);
        csr_src[p] = src[i];
    }
}

// ---------------------------------------------------------------------------
// GEMM + fused alpha epilogue (analytically near compute floor: ~13-15us).
// 256 threads; block tile 64 rows x 128 cols; thread tile 4 rows x 8 cols.
// ---------------------------------------------------------------------------
template <int H>
__global__ __launch_bounds__(256) void gemm128_kernel(
    const float* __restrict__ X, const float* __restrict__ W,
    const float* __restrict__ asrc, const float* __restrict__ adst,
    float* __restrict__ Hout, float* __restrict__ alpha_s,
    float* __restrict__ alpha_d, int N) {
    __shared__ float sX[64 * 132];
    __shared__ float sW[64 * 132];
    int t = threadIdx.x;
    int tx = t & 15;
    int ty = t >> 4;
    int row0 = blockIdx.x * 64;

    const float4* X4 = (const float4*)X;
#pragma unroll
    for (int it = 0; it < 8; ++it) {
        int idx = t + it * 256;
        int r = idx >> 5;
        int q = idx & 31;
        int row = row0 + r;
        float4 v = make_float4(0.f, 0.f, 0.f, 0.f);
        if (row < N) v = X4[(size_t)row * 32 + q];
        *(float4*)&sX[r * 132 + q * 4] = v;
    }

    float acc[4][8] = {};
    const float4* W4 = (const float4*)W;

    for (int p = 0; p < 2; ++p) {
#pragma unroll
        for (int it = 0; it < 8; ++it) {
            int idx = t + it * 256;
            int kk = idx >> 5;
            int q = idx & 31;
            float4 v = W4[(p * 64 + kk) * 32 + q];
            *(float4*)&sW[kk * 132 + q * 4] = v;
        }
        __syncthreads();

        for (int k4 = 0; k4 < 64; k4 += 4) {
            float4 a[4];
#pragma unroll
            for (int i = 0; i < 4; ++i)
                a[i] = *(const float4*)&sX[(i * 16 + ty) * 132 + p * 64 + k4];
#pragma unroll
            for (int kk = 0; kk < 4; ++kk) {
                float4 b0 = *(const float4*)&sW[(k4 + kk) * 132 + tx * 8];
                float4 b1 = *(const float4*)&sW[(k4 + kk) * 132 + tx * 8 + 4];
#pragma unroll
                for (int i = 0; i < 4; ++i) {
                    float av = ((const float*)&a[i])[kk];
                    acc[i][0] += av * b0.x;
                    acc[i][1] += av * b0.y;
                    acc[i][2] += av * b0.z;
                    acc[i][3] += av * b0.w;
                    acc[i][4] += av * b1.x;
                    acc[i][5] += av * b1.y;
                    acc[i][6] += av * b1.z;
                    acc[i][7] += av * b1.w;
                }
            }
        }
        __syncthreads();
    }

#pragma unroll
    for (int i = 0; i < 4; ++i) {
        int row = row0 + i * 16 + ty;
        if (row < N) {
            float4 o0 = make_float4(acc[i][0], acc[i][1], acc[i][2], acc[i][3]);
            float4 o1 = make_float4(acc[i][4], acc[i][5], acc[i][6], acc[i][7]);
            ((float4*)Hout)[(size_t)row * 32 + tx * 2] = o0;
            ((float4*)Hout)[(size_t)row * 32 + tx * 2 + 1] = o1;
        }
    }

    constexpr int RW = (H == 4) ? 4 : 16;  // tx lanes per head (C/8)
    float4 av0 = ((const float4*)asrc)[tx * 2];
    float4 av1 = ((const float4*)asrc)[tx * 2 + 1];
    float4 dv0 = ((const float4*)adst)[tx * 2];
    float4 dv1 = ((const float4*)adst)[tx * 2 + 1];
#pragma unroll
    for (int i = 0; i < 4; ++i) {
        float ps = acc[i][0] * av0.x + acc[i][1] * av0.y + acc[i][2] * av0.z +
                   acc[i][3] * av0.w + acc[i][4] * av1.x + acc[i][5] * av1.y +
                   acc[i][6] * av1.z + acc[i][7] * av1.w;
        float pd = acc[i][0] * dv0.x + acc[i][1] * dv0.y + acc[i][2] * dv0.z +
                   acc[i][3] * dv0.w + acc[i][4] * dv1.x + acc[i][5] * dv1.y +
                   acc[i][6] * dv1.z + acc[i][7] * dv1.w;
#pragma unroll
        for (int o = 1; o < RW; o <<= 1) {
            ps += __shfl_xor(ps, o);
            pd += __shfl_xor(pd, o);
        }
        if ((tx & (RW - 1)) == 0) {
            int row = row0 + i * 16 + ty;
            if (row < N) {
                int hh = tx / RW;
                alpha_s[(size_t)row * H + hh] = ps;
                alpha_d[(size_t)row * H + hh] = pd;
            }
        }
    }
}

// ---------------------------------------------------------------------------
// Per-dst-node segment softmax + aggregation. TWO nodes per wave (32 lanes
// each; 4 nodes per 128-thread block) -- two independent latency chains
// overlap per wave. Lane owns a float4 channel group (16B coalesced loads).
// Degree<=32 fast path keeps s/exp in registers; fallback loops for larger.
// Shuffle reductions use xor<=16 (stay within the 32-lane half).
// ---------------------------------------------------------------------------
template <int H>
__global__ __launch_bounds__(128) void gather_kernel(
    const float* __restrict__ h, const float* __restrict__ as_,
    const float* __restrict__ ad_, const int* __restrict__ off,
    const int* __restrict__ csr_src, const float* __restrict__ bias,
    float* __restrict__ out, int N) {
    __shared__ int s_src[4][32];
    __shared__ float s_w[4][32 * H];
    int t = threadIdx.x;
    int wv = t >> 6;           // wave 0..1
    int lane = t & 63;
    int hw = lane >> 5;        // half-wave 0..1
    int l = lane & 31;         // lane within half
    int sub = wv * 2 + hw;     // node slot 0..3
    int n = blockIdx.x * 4 + sub;
    if (n >= N) return;

    int beg = off[n];
    int total = off[n + 1] - beg + 1;  // + self loop
    int total0 = min(total, 32);

    float adv[H];
#pragma unroll
    for (int hh = 0; hh < H; ++hh) adv[hh] = ad_[(size_t)n * H + hh];

    // Phase A: first 32 edges -> registers; stage src; per-head max
    float sv[H];
    float m[H];
#pragma unroll
    for (int hh = 0; hh < H; ++hh) m[hh] = -3.4e38f;
    if (l < total0) {
        int src = (l == 0) ? n : csr_src[beg + l - 1];
        s_src[sub][l] = src;
        if (H == 4) {
            float4 a4 = ((const float4*)as_)[src];
            sv[0] = a4.x + adv[0];
            sv[1] = a4.y + adv[1];
            sv[2] = a4.z + adv[2];
            sv[3] = a4.w + adv[3];
        } else {
            sv[0] = as_[src] + adv[0];
        }
#pragma unroll
        for (int hh = 0; hh < H; ++hh) {
            float s = sv[hh];
            s = (s > 0.f) ? s : NEG_SLOPE * s;
            sv[hh] = s;
            m[hh] = s;
        }
    }
    for (int idx = l + 32; idx < total; idx += 32) {  // deg>32 fallback
        int src = csr_src[beg + idx - 1];
#pragma unroll
        for (int hh = 0; hh < H; ++hh) {
            float s = as_[(size_t)src * H + hh] + adv[hh];
            s = (s > 0.f) ? s : NEG_SLOPE * s;
            m[hh] = fmaxf(m[hh], s);
        }
    }
#pragma unroll
    for (int o = 16; o > 0; o >>= 1)
#pragma unroll
        for (int hh = 0; hh < H; ++hh) m[hh] = fmaxf(m[hh], __shfl_xor(m[hh], o));

    // Phase B: sum of exp
    float p[H];
    float dsum[H];
#pragma unroll
    for (int hh = 0; hh < H; ++hh) dsum[hh] = 0.f;
    if (l < total0) {
#pragma unroll
        for (int hh = 0; hh < H; ++hh) {
            p[hh] = __expf(sv[hh] - m[hh]);
            dsum[hh] = p[hh];
        }
    }
    for (int idx = l + 32; idx < total; idx += 32) {
        int src = csr_src[beg + idx - 1];
#pragma unroll
        for (int hh = 0; hh < H; ++hh) {
            float s = as_[(size_t)src * H + hh] + adv[hh];
            s = (s > 0.f) ? s : NEG_SLOPE * s;
            dsum[hh] += __expf(s - m[hh]);
        }
    }
#pragma unroll
    for (int o = 16; o > 0; o >>= 1)
#pragma unroll
        for (int hh = 0; hh < H; ++hh) dsum[hh] += __shfl_xor(dsum[hh], o);
    float inv[H];
#pragma unroll
    for (int hh = 0; hh < H; ++hh) inv[hh] = 1.f / dsum[hh];

    if (l < total0) {
#pragma unroll
        for (int hh = 0; hh < H; ++hh) s_w[sub][l * H + hh] = p[hh] * inv[hh];
    }

    // Phase C: weighted accumulation; lane owns channels 4l..4l+3 (one head)
    const int head_t = (H == 1) ? 0 : (l >> 3);
    float4 acc = make_float4(0.f, 0.f, 0.f, 0.f);
    const float4* __restrict__ h4 = (const float4*)h;
    for (int base = 0; base < total; base += 32) {
        int cnt2 = min(32, total - base);
        if (base > 0 && l < cnt2) {  // deg>32 fallback: restage
            int src = csr_src[beg + base + l - 1];
            s_src[sub][l] = src;
#pragma unroll
            for (int hh = 0; hh < H; ++hh) {
                float s = as_[(size_t)src * H + hh] + adv[hh];
                s = (s > 0.f) ? s : NEG_SLOPE * s;
                s_w[sub][l * H + hh] = __expf(s - m[hh]) * inv[hh];
            }
        }
        __builtin_amdgcn_wave_barrier();
        int j = 0;
        for (; j + 4 <= cnt2; j += 4) {
            int t0 = s_src[sub][j + 0], t1 = s_src[sub][j + 1];
            int t2 = s_src[sub][j + 2], t3 = s_src[sub][j + 3];
            float w0 = s_w[sub][(j + 0) * H + head_t];
            float w1 = s_w[sub][(j + 1) * H + head_t];
            float w2 = s_w[sub][(j + 2) * H + head_t];
            float w3 = s_w[sub][(j + 3) * H + head_t];
            float4 v0 = h4[(size_t)t0 * 32 + l];
            float4 v1 = h4[(size_t)t1 * 32 + l];
            float4 v2 = h4[(size_t)t2 * 32 + l];
            float4 v3 = h4[(size_t)t3 * 32 + l];
            acc.x += w0 * v0.x; acc.y += w0 * v0.y;
            acc.z += w0 * v0.z; acc.w += w0 * v0.w;
            acc.x += w1 * v1.x; acc.y += w1 * v1.y;
            acc.z += w1 * v1.z; acc.w += w1 * v1.w;
            acc.x += w2 * v2.x; acc.y += w2 * v2.y;
            acc.z += w2 * v2.z; acc.w += w2 * v2.w;
            acc.x += w3 * v3.x; acc.y += w3 * v3.y;
            acc.z += w3 * v3.z; acc.w += w3 * v3.w;
        }
        for (; j < cnt2; ++j) {
            int sj = s_src[sub][j];
            float wj = s_w[sub][j * H + head_t];
            float4 hv = h4[(size_t)sj * 32 + l];
            acc.x += wj * hv.x; acc.y += wj * hv.y;
            acc.z += wj * hv.z; acc.w += wj * hv.w;
        }
        __builtin_amdgcn_wave_barrier();
    }
    float4 bv = ((const float4*)bias)[l];
    float4 o4;
    o4.x = fmaxf(acc.x + bv.x, 0.f);
    o4.y = fmaxf(acc.y + bv.y, 0.f);
    o4.z = fmaxf(acc.z + bv.z, 0.f);
    o4.w = fmaxf(acc.w + bv.w, 0.f);
    ((float4*)out)[(size_t)n * 32 + l] = o4;
}

// ---------------------------------------------------------------------------
extern "C" void kernel_launch(void* const* d_in, const int* in_sizes, int n_in,
                              void* d_out, int out_size, void* d_ws,
                              size_t ws_size, hipStream_t stream) {
    const float* x   = (const float*)d_in[0];
    const void*  ei  = d_in[1];
    const float* W0  = (const float*)d_in[2];
    const float* as0 = (const float*)d_in[3];
    const float* ad0 = (const float*)d_in[4];
    const float* b0  = (const float*)d_in[5];
    const float* W1  = (const float*)d_in[6];
    const float* as1 = (const float*)d_in[7];
    const float* ad1 = (const float*)d_in[8];
    const float* b1  = (const float*)d_in[9];
    const float* W2  = (const float*)d_in[10];
    const float* as2 = (const float*)d_in[11];
    const float* ad2 = (const float*)d_in[12];
    const float* b2  = (const float*)d_in[13];

    int N = in_sizes[0] / 128;
    int E = in_sizes[1] / 2;
    float* out = (float*)d_out;

    // workspace layout
    float* h       = (float*)d_ws;                       // N*128
    float* alpha_s = h + (size_t)N * 128;                // N*4 (max H)
    float* alpha_d = alpha_s + (size_t)N * 4;            // N*4
    int*   cnt     = (int*)(alpha_d + (size_t)N * 4);    // N
    int*   off     = cnt + N;                            // N+1
    int*   cursor  = off + N + 1;                        // N
    int*   partial = cursor + N;                         // SCAN_NB
    int*   src32   = partial + SCAN_NB;                  // E
    int*   dst32   = src32 + E;                          // E
    int*   csr     = dst32 + E;                          // E

    int eb = (E + 255) / 256;
    int nb = (N + 255) / 256;

    zero_kernel<<<nb, 256, 0, stream>>>(cnt, N);
    detect_convert_count_kernel<<<eb, 256, 0, stream>>>(ei, E, src32, dst32, cnt);
    scan1_kernel<<<SCAN_NB, 256, 0, stream>>>(cnt, partial, N);
    scan3_kernel<<<SCAN_NB, 256, 0, stream>>>(cnt, partial, off, cursor, N);
    scatter_kernel<<<eb, 256, 0, stream>>>(src32, dst32, E, cursor, csr);

    int gb = (N + 63) / 64;
    int wb = (N + 3) / 4;  // 4 nodes per 128-thread block (2 per wave)

    // layer 0: H=4
    gemm128_kernel<4><<<gb, 256, 0, stream>>>(x, W0, as0, ad0, h, alpha_s, alpha_d, N);
    gather_kernel<4><<<wb, 128, 0, stream>>>(h, alpha_s, alpha_d, off, csr, b0, out, N);

    // layer 1: H=4
    gemm128_kernel<4><<<gb, 256, 0, stream>>>(out, W1, as1, ad1, h, alpha_s, alpha_d, N);
    gather_kernel<4><<<wb, 128, 0, stream>>>(h, alpha_s, alpha_d, off, csr, b1, out, N);

    // layer 2: H=1
    gemm128_kernel<1><<<gb, 256, 0, stream>>>(out, W2, as2, ad2, h, alpha_s, alpha_d, N);
    gather_kernel<1><<<wb, 128, 0, stream>>>(h, alpha_s, alpha_d, off, csr, b2, out, N);
}

// Round 8
// 444.444 us; speedup vs baseline: 2.3621x; 1.0608x over previous
//
#include <hip/hip_runtime.h>

#define NEG_SLOPE 0.2f
#define CAP 64  // bucket capacity per node; overflow handled exactly

// ---------------------------------------------------------------------------
__global__ void zero_kernel(int* __restrict__ p, int n) {
    int i = blockIdx.x * blockDim.x + threadIdx.x;
    if (i < n) p[i] = 0;
}

// ---------------------------------------------------------------------------
// One-pass adjacency build: detect int32/int64, bucket edges by dst.
// cnt[d] ends as the full in-degree; bucket holds the first CAP srcs;
// the rest spill to an exact overflow list (practically never at lambda~16).
// ---------------------------------------------------------------------------
__global__ void build_kernel(const void* __restrict__ ei_raw, int E,
                             int* __restrict__ cnt, int* __restrict__ bucket,
                             int* __restrict__ ovf_src,
                             int* __restrict__ ovf_dst,
                             int* __restrict__ ovf_cnt) {
    const int* as32 = (const int*)ei_raw;
    const long long* as64 = (const long long*)ei_raw;
    bool is64 = true;
    for (int i = 0; i < 16; ++i) {
        long long v = as64[i];
        if (!(v >= 0 && v < 2147483648LL)) { is64 = false; }
    }
    int i = blockIdx.x * blockDim.x + threadIdx.x;
    if (i < E) {
        int s, d;
        if (is64) {
            s = (int)as64[i];
            d = (int)as64[(size_t)E + i];
        } else {
            s = as32[i];
            d = as32[(size_t)E + i];
        }
        int p = atomicAdd(&cnt[d], 1);
        if (p < CAP) {
            bucket[(size_t)d * CAP + p] = s;
        } else {
            int q = atomicAdd(ovf_cnt, 1);
            ovf_src[q] = s;
            ovf_dst[q] = d;
        }
    }
}

// ---------------------------------------------------------------------------
// GEMM + fused alpha epilogue. 256 threads; 64 rows x 128 cols per block;
// thread tile 4 rows x 8 cols; X and W staged in LDS.
// ---------------------------------------------------------------------------
template <int H>
__global__ __launch_bounds__(256) void gemm128_kernel(
    const float* __restrict__ X, const float* __restrict__ W,
    const float* __restrict__ asrc, const float* __restrict__ adst,
    float* __restrict__ Hout, float* __restrict__ alpha_s,
    float* __restrict__ alpha_d, int N) {
    __shared__ float sX[64 * 132];
    __shared__ float sW[64 * 132];
    int t = threadIdx.x;
    int tx = t & 15;
    int ty = t >> 4;
    int row0 = blockIdx.x * 64;

    const float4* X4 = (const float4*)X;
#pragma unroll
    for (int it = 0; it < 8; ++it) {
        int idx = t + it * 256;
        int r = idx >> 5;
        int q = idx & 31;
        int row = row0 + r;
        float4 v = make_float4(0.f, 0.f, 0.f, 0.f);
        if (row < N) v = X4[(size_t)row * 32 + q];
        *(float4*)&sX[r * 132 + q * 4] = v;
    }

    float acc[4][8] = {};
    const float4* W4 = (const float4*)W;

    for (int p = 0; p < 2; ++p) {
#pragma unroll
        for (int it = 0; it < 8; ++it) {
            int idx = t + it * 256;
            int kk = idx >> 5;
            int q = idx & 31;
            float4 v = W4[(p * 64 + kk) * 32 + q];
            *(float4*)&sW[kk * 132 + q * 4] = v;
        }
        __syncthreads();

        for (int k4 = 0; k4 < 64; k4 += 4) {
            float4 a[4];
#pragma unroll
            for (int i = 0; i < 4; ++i)
                a[i] = *(const float4*)&sX[(i * 16 + ty) * 132 + p * 64 + k4];
#pragma unroll
            for (int kk = 0; kk < 4; ++kk) {
                float4 b0 = *(const float4*)&sW[(k4 + kk) * 132 + tx * 8];
                float4 b1 = *(const float4*)&sW[(k4 + kk) * 132 + tx * 8 + 4];
#pragma unroll
                for (int i = 0; i < 4; ++i) {
                    float av = ((const float*)&a[i])[kk];
                    acc[i][0] += av * b0.x;
                    acc[i][1] += av * b0.y;
                    acc[i][2] += av * b0.z;
                    acc[i][3] += av * b0.w;
                    acc[i][4] += av * b1.x;
                    acc[i][5] += av * b1.y;
                    acc[i][6] += av * b1.z;
                    acc[i][7] += av * b1.w;
                }
            }
        }
        __syncthreads();
    }

#pragma unroll
    for (int i = 0; i < 4; ++i) {
        int row = row0 + i * 16 + ty;
        if (row < N) {
            float4 o0 = make_float4(acc[i][0], acc[i][1], acc[i][2], acc[i][3]);
            float4 o1 = make_float4(acc[i][4], acc[i][5], acc[i][6], acc[i][7]);
            ((float4*)Hout)[(size_t)row * 32 + tx * 2] = o0;
            ((float4*)Hout)[(size_t)row * 32 + tx * 2 + 1] = o1;
        }
    }

    constexpr int RW = (H == 4) ? 4 : 16;  // tx lanes per head (C/8)
    float4 av0 = ((const float4*)asrc)[tx * 2];
    float4 av1 = ((const float4*)asrc)[tx * 2 + 1];
    float4 dv0 = ((const float4*)adst)[tx * 2];
    float4 dv1 = ((const float4*)adst)[tx * 2 + 1];
#pragma unroll
    for (int i = 0; i < 4; ++i) {
        float ps = acc[i][0] * av0.x + acc[i][1] * av0.y + acc[i][2] * av0.z +
                   acc[i][3] * av0.w + acc[i][4] * av1.x + acc[i][5] * av1.y +
                   acc[i][6] * av1.z + acc[i][7] * av1.w;
        float pd = acc[i][0] * dv0.x + acc[i][1] * dv0.y + acc[i][2] * dv0.z +
                   acc[i][3] * dv0.w + acc[i][4] * dv1.x + acc[i][5] * dv1.y +
                   acc[i][6] * dv1.z + acc[i][7] * dv1.w;
#pragma unroll
        for (int o = 1; o < RW; o <<= 1) {
            ps += __shfl_xor(ps, o);
            pd += __shfl_xor(pd, o);
        }
        if ((tx & (RW - 1)) == 0) {
            int row = row0 + i * 16 + ty;
            if (row < N) {
                int hh = tx / RW;
                alpha_s[(size_t)row * H + hh] = ps;
                alpha_d[(size_t)row * H + hh] = pd;
            }
        }
    }
}

// ---------------------------------------------------------------------------
// Segment softmax + aggregation from the bucket table. Two nodes per wave
// (32 lanes each). Edge idx 0 = self-loop; idx 1..deg from bucket (first CAP)
// and the exact overflow list (deg>CAP only). Phase C unrolled x8 for MLP.
// ---------------------------------------------------------------------------
template <int H>
__global__ __launch_bounds__(128) void gather_kernel(
    const float* __restrict__ h, const float* __restrict__ as_,
    const float* __restrict__ ad_, const int* __restrict__ cnt,
    const int* __restrict__ bucket, const int* __restrict__ ovf_src,
    const int* __restrict__ ovf_dst, const int* __restrict__ ovf_cnt,
    const float* __restrict__ bias, float* __restrict__ out, int N) {
    __shared__ int s_src[4][32];
    __shared__ float s_w[4][32 * H];
    int t = threadIdx.x;
    int wv = t >> 6;
    int lane = t & 63;
    int hw = lane >> 5;
    int l = lane & 31;
    int sub = wv * 2 + hw;
    int n = blockIdx.x * 4 + sub;
    if (n >= N) return;

    int deg = cnt[n];
    int total = deg + 1;                 // + self loop
    int totalb = min(deg, CAP) + 1;      // edges reachable via bucket
    int onum = (deg > CAP) ? *ovf_cnt : 0;  // uniform per node
    const int* bk = bucket + (size_t)n * CAP;

    float adv[H];
#pragma unroll
    for (int hh = 0; hh < H; ++hh) adv[hh] = ad_[(size_t)n * H + hh];

    // Phase A: first 32 edges -> registers; stage src; per-head max
    float sv[H];
    float m[H];
#pragma unroll
    for (int hh = 0; hh < H; ++hh) m[hh] = -3.4e38f;
    int total0 = min(total, 32);
    if (l < total0) {
        int src = (l == 0) ? n : bk[l - 1];
        s_src[sub][l] = src;
        if (H == 4) {
            float4 a4 = ((const float4*)as_)[src];
            sv[0] = a4.x + adv[0];
            sv[1] = a4.y + adv[1];
            sv[2] = a4.z + adv[2];
            sv[3] = a4.w + adv[3];
        } else {
            sv[0] = as_[src] + adv[0];
        }
#pragma unroll
        for (int hh = 0; hh < H; ++hh) {
            float s = sv[hh];
            s = (s > 0.f) ? s : NEG_SLOPE * s;
            sv[hh] = s;
            m[hh] = s;
        }
    }
    for (int idx = l + 32; idx < totalb; idx += 32) {  // deg>31 fallback
        int src = bk[idx - 1];
#pragma unroll
        for (int hh = 0; hh < H; ++hh) {
            float s = as_[(size_t)src * H + hh] + adv[hh];
            s = (s > 0.f) ? s : NEG_SLOPE * s;
            m[hh] = fmaxf(m[hh], s);
        }
    }
    for (int e = 0; e < onum; ++e) {  // exact overflow path (deg>CAP only)
        if (ovf_dst[e] == n && l == 0) {
            int src = ovf_src[e];
#pragma unroll
            for (int hh = 0; hh < H; ++hh) {
                float s = as_[(size_t)src * H + hh] + adv[hh];
                s = (s > 0.f) ? s : NEG_SLOPE * s;
                m[hh] = fmaxf(m[hh], s);
            }
        }
    }
#pragma unroll
    for (int o = 16; o > 0; o >>= 1)
#pragma unroll
        for (int hh = 0; hh < H; ++hh) m[hh] = fmaxf(m[hh], __shfl_xor(m[hh], o));

    // Phase B: sum of exp
    float p[H];
    float dsum[H];
#pragma unroll
    for (int hh = 0; hh < H; ++hh) dsum[hh] = 0.f;
    if (l < total0) {
#pragma unroll
        for (int hh = 0; hh < H; ++hh) {
            p[hh] = __expf(sv[hh] - m[hh]);
            dsum[hh] = p[hh];
        }
    }
    for (int idx = l + 32; idx < totalb; idx += 32) {
        int src = bk[idx - 1];
#pragma unroll
        for (int hh = 0; hh < H; ++hh) {
            float s = as_[(size_t)src * H + hh] + adv[hh];
            s = (s > 0.f) ? s : NEG_SLOPE * s;
            dsum[hh] += __expf(s - m[hh]);
        }
    }
    for (int e = 0; e < onum; ++e) {
        if (ovf_dst[e] == n && l == 0) {
            int src = ovf_src[e];
#pragma unroll
            for (int hh = 0; hh < H; ++hh) {
                float s = as_[(size_t)src * H + hh] + adv[hh];
                s = (s > 0.f) ? s : NEG_SLOPE * s;
                dsum[hh] += __expf(s - m[hh]);
            }
        }
    }
#pragma unroll
    for (int o = 16; o > 0; o >>= 1)
#pragma unroll
        for (int hh = 0; hh < H; ++hh) dsum[hh] += __shfl_xor(dsum[hh], o);
    float inv[H];
#pragma unroll
    for (int hh = 0; hh < H; ++hh) inv[hh] = 1.f / dsum[hh];

    if (l < total0) {
#pragma unroll
        for (int hh = 0; hh < H; ++hh) s_w[sub][l * H + hh] = p[hh] * inv[hh];
    }

    // Phase C: weighted accumulation; lane owns channels 4l..4l+3 (one head)
    const int head_t = (H == 1) ? 0 : (l >> 3);
    float4 acc = make_float4(0.f, 0.f, 0.f, 0.f);
    const float4* __restrict__ h4 = (const float4*)h;
    for (int base = 0; base < totalb; base += 32) {
        int cnt2 = min(32, totalb - base);
        if (base > 0 && l < cnt2) {  // restage (deg>31 fallback)
            int src = bk[base + l - 1];
            s_src[sub][l] = src;
#pragma unroll
            for (int hh = 0; hh < H; ++hh) {
                float s = as_[(size_t)src * H + hh] + adv[hh];
                s = (s > 0.f) ? s : NEG_SLOPE * s;
                s_w[sub][l * H + hh] = __expf(s - m[hh]) * inv[hh];
            }
        }
        __builtin_amdgcn_wave_barrier();
        int j = 0;
        for (; j + 8 <= cnt2; j += 8) {
            int ts[8];
            float ws[8];
            float4 vs[8];
#pragma unroll
            for (int u = 0; u < 8; ++u) {
                ts[u] = s_src[sub][j + u];
                ws[u] = s_w[sub][(j + u) * H + head_t];
            }
#pragma unroll
            for (int u = 0; u < 8; ++u) vs[u] = h4[(size_t)ts[u] * 32 + l];
#pragma unroll
            for (int u = 0; u < 8; ++u) {
                acc.x += ws[u] * vs[u].x;
                acc.y += ws[u] * vs[u].y;
                acc.z += ws[u] * vs[u].z;
                acc.w += ws[u] * vs[u].w;
            }
        }
        for (; j + 4 <= cnt2; j += 4) {
            int ts[4];
            float ws[4];
            float4 vs[4];
#pragma unroll
            for (int u = 0; u < 4; ++u) {
                ts[u] = s_src[sub][j + u];
                ws[u] = s_w[sub][(j + u) * H + head_t];
            }
#pragma unroll
            for (int u = 0; u < 4; ++u) vs[u] = h4[(size_t)ts[u] * 32 + l];
#pragma unroll
            for (int u = 0; u < 4; ++u) {
                acc.x += ws[u] * vs[u].x;
                acc.y += ws[u] * vs[u].y;
                acc.z += ws[u] * vs[u].z;
                acc.w += ws[u] * vs[u].w;
            }
        }
        for (; j < cnt2; ++j) {
            int sj = s_src[sub][j];
            float wj = s_w[sub][j * H + head_t];
            float4 hv = h4[(size_t)sj * 32 + l];
            acc.x += wj * hv.x; acc.y += wj * hv.y;
            acc.z += wj * hv.z; acc.w += wj * hv.w;
        }
        __builtin_amdgcn_wave_barrier();
    }
    for (int e = 0; e < onum; ++e) {  // exact overflow accumulate
        if (ovf_dst[e] == n) {
            int src = ovf_src[e];
            int hh = head_t;
            float s = as_[(size_t)src * H + hh] + adv[hh];
            s = (s > 0.f) ? s : NEG_SLOPE * s;
            float wj = __expf(s - m[hh]) * inv[hh];
            float4 hv = h4[(size_t)src * 32 + l];
            acc.x += wj * hv.x; acc.y += wj * hv.y;
            acc.z += wj * hv.z; acc.w += wj * hv.w;
        }
    }
    float4 bv = ((const float4*)bias)[l];
    float4 o4;
    o4.x = fmaxf(acc.x + bv.x, 0.f);
    o4.y = fmaxf(acc.y + bv.y, 0.f);
    o4.z = fmaxf(acc.z + bv.z, 0.f);
    o4.w = fmaxf(acc.w + bv.w, 0.f);
    ((float4*)out)[(size_t)n * 32 + l] = o4;
}

// ---------------------------------------------------------------------------
extern "C" void kernel_launch(void* const* d_in, const int* in_sizes, int n_in,
                              void* d_out, int out_size, void* d_ws,
                              size_t ws_size, hipStream_t stream) {
    const float* x   = (const float*)d_in[0];
    const void*  ei  = d_in[1];
    const float* W0  = (const float*)d_in[2];
    const float* as0 = (const float*)d_in[3];
    const float* ad0 = (const float*)d_in[4];
    const float* b0  = (const float*)d_in[5];
    const float* W1  = (const float*)d_in[6];
    const float* as1 = (const float*)d_in[7];
    const float* ad1 = (const float*)d_in[8];
    const float* b1  = (const float*)d_in[9];
    const float* W2  = (const float*)d_in[10];
    const float* as2 = (const float*)d_in[11];
    const float* ad2 = (const float*)d_in[12];
    const float* b2  = (const float*)d_in[13];

    int N = in_sizes[0] / 128;
    int E = in_sizes[1] / 2;
    float* out = (float*)d_out;

    // workspace layout (~47 MB)
    float* h       = (float*)d_ws;                       // N*128
    float* alpha_s = h + (size_t)N * 128;                // N*4 (max H)
    float* alpha_d = alpha_s + (size_t)N * 4;            // N*4
    int*   cnt     = (int*)(alpha_d + (size_t)N * 4);    // N
    int*   ovf_c   = cnt + N;                            // 1
    int*   bucket  = ovf_c + 1;                          // N*CAP
    int*   ovf_src = bucket + (size_t)N * CAP;           // E
    int*   ovf_dst = ovf_src + E;                        // E

    int eb = (E + 255) / 256;
    int nb = (N + 1 + 255) / 256;

    zero_kernel<<<nb, 256, 0, stream>>>(cnt, N + 1);  // cnt + ovf counter
    build_kernel<<<eb, 256, 0, stream>>>(ei, E, cnt, bucket, ovf_src, ovf_dst, ovf_c);

    int gb = (N + 63) / 64;
    int wb = (N + 3) / 4;  // 4 nodes per 128-thread block (2 per wave)

    // layer 0: H=4
    gemm128_kernel<4><<<gb, 256, 0, stream>>>(x, W0, as0, ad0, h, alpha_s, alpha_d, N);
    gather_kernel<4><<<wb, 128, 0, stream>>>(h, alpha_s, alpha_d, cnt, bucket,
                                             ovf_src, ovf_dst, ovf_c, b0, out, N);

    // layer 1: H=4
    gemm128_kernel<4><<<gb, 256, 0, stream>>>(out, W1, as1, ad1, h, alpha_s, alpha_d, N);
    gather_kernel<4><<<wb, 128, 0, stream>>>(h, alpha_s, alpha_d, cnt, bucket,
                                             ovf_src, ovf_dst, ovf_c, b1, out, N);

    // layer 2: H=1
    gemm128_kernel<1><<<gb, 256, 0, stream>>>(out, W2, as2, ad2, h, alpha_s, alpha_d, N);
    gather_kernel<1><<<wb, 128, 0, stream>>>(h, alpha_s, alpha_d, cnt, bucket,
                                             ovf_src, ovf_dst, ovf_c, b2, out, N);
}